// Round 10
// baseline (81.390 us; speedup 1.0000x reference)
//
#include <hip/hip_runtime.h>

// B=256, Q=16. v[idx] = prod_q cols[q][bit], qubit 0 = MSB.
// i = idx>>8 (qubits 0..7), j = idx&255 (qubits 8..15): v = A[i]*Bv[j].
// Output: fp32 real part, [B, 65536] (locked in since R7; R9 absmax 4.9e-4).
//
// R10: producer/consumer split. R9 kernel ~22us vs 10.6us write roofline
// (~3.3 TB/s): theory = per-block prologue (divergent sincos, 2 barriers,
// cmul chains) x4096 blocks limits store issue. Kernel1 builds A/Bv tables
// (1 MB) in d_ws once per batch; kernel2 is a pure streamer (no LDS/barriers):
// 2 float4 Bv loads + 4 wave-uniform A loads + 4 nt float4 stores per thread.

typedef __attribute__((ext_vector_type(4))) float fvec4;   // 16 B, nt-storable

__device__ __forceinline__ float2 cmul(float2 a, float2 b) {
    return make_float2(fmaf(a.x, b.x, -a.y * b.y),
                       fmaf(a.x, b.y,  a.y * b.x));
}

// ---- kernel 1: per-batch prefix tables A (qubits 0..7), Bv (qubits 8..15) ----
// grid (B), block 256. wsA[b*256+i], wsB[b*256+j] as float2.
__global__ __launch_bounds__(256) void build_tables(
        const float* __restrict__ ry, const float* __restrict__ rz,
        float2* __restrict__ wsA, float2* __restrict__ wsB) {
    __shared__ float2 cols[16][2];
    const int b = blockIdx.x, t = threadIdx.x;
    if (t < 16) {
        float hry = 0.5f * ry[b * 16 + t];
        float hrz = 0.5f * rz[b * 16 + t];
        float s, c, sz, cz;
        sincosf(hry, &s, &c);
        sincosf(hrz, &sz, &cz);
        cols[t][0] = make_float2(c * cz, -c * sz);  // cos(ry/2) e^{-i rz/2}
        cols[t][1] = make_float2(s * cz,  s * sz);  // sin(ry/2) e^{+i rz/2}
    }
    __syncthreads();
    float2 a = cols[0][(t >> 7) & 1];
    #pragma unroll
    for (int q = 1; q < 8; ++q) a = cmul(a, cols[q][(t >> (7 - q)) & 1]);
    wsA[b * 256 + t] = a;
    float2 bv = cols[8][(t >> 7) & 1];
    #pragma unroll
    for (int q = 9; q < 16; ++q) bv = cmul(bv, cols[q][(t >> (15 - q)) & 1]);
    wsB[b * 256 + t] = bv;
}

// ---- kernel 2: pure outer-product streamer ----
// grid (B, 16), block 256. Block = batch b, 16 rows at slice*16.
// Thread: jp = t&63 (float4 chunk in row), wv = t>>6 -> rows row0..row0+3.
// Loads: Bv cols 4jp..4jp+3 as 2 float4 (wave spans 2 KB contiguous, L1/L2-hot
// after first touch); A[row] wave-uniform (L1 broadcast). 4 nt stores.
__global__ __launch_bounds__(256) void stream_outer(
        const float2* __restrict__ wsA, const float2* __restrict__ wsB,
        fvec4* __restrict__ out) {
    const int b = blockIdx.x, slice = blockIdx.y, t = threadIdx.x;
    const int jp = t & 63;
    const int wv = t >> 6;
    const int row0 = slice * 16 + wv * 4;

    const fvec4* bt = (const fvec4*)(wsB + b * 256) + 2 * jp;
    const fvec4 bl0 = bt[0];            // (b0.re,b0.im,b1.re,b1.im)
    const fvec4 bl1 = bt[1];            // (b2.re,b2.im,b3.re,b3.im)
    const float2* at = wsA + b * 256 + row0;
    const float2 a0 = at[0], a1 = at[1], a2 = at[2], a3 = at[3];

    fvec4* outb = out + (size_t)b * 16384 + (size_t)row0 * 64 + jp;
    fvec4 w0, w1, w2, w3;
    w0[0] = fmaf(a0.x, bl0[0], -a0.y * bl0[1]);
    w0[1] = fmaf(a0.x, bl0[2], -a0.y * bl0[3]);
    w0[2] = fmaf(a0.x, bl1[0], -a0.y * bl1[1]);
    w0[3] = fmaf(a0.x, bl1[2], -a0.y * bl1[3]);
    w1[0] = fmaf(a1.x, bl0[0], -a1.y * bl0[1]);
    w1[1] = fmaf(a1.x, bl0[2], -a1.y * bl0[3]);
    w1[2] = fmaf(a1.x, bl1[0], -a1.y * bl1[1]);
    w1[3] = fmaf(a1.x, bl1[2], -a1.y * bl1[3]);
    w2[0] = fmaf(a2.x, bl0[0], -a2.y * bl0[1]);
    w2[1] = fmaf(a2.x, bl0[2], -a2.y * bl0[3]);
    w2[2] = fmaf(a2.x, bl1[0], -a2.y * bl1[1]);
    w2[3] = fmaf(a2.x, bl1[2], -a2.y * bl1[3]);
    w3[0] = fmaf(a3.x, bl0[0], -a3.y * bl0[1]);
    w3[1] = fmaf(a3.x, bl0[2], -a3.y * bl0[3]);
    w3[2] = fmaf(a3.x, bl1[0], -a3.y * bl1[1]);
    w3[3] = fmaf(a3.x, bl1[2], -a3.y * bl1[3]);
    __builtin_nontemporal_store(w0, outb +   0);
    __builtin_nontemporal_store(w1, outb +  64);
    __builtin_nontemporal_store(w2, outb + 128);
    __builtin_nontemporal_store(w3, outb + 192);
}

// ---- fallback (out_size == 2^25 fp32): interleaved re/im from tables ----
__global__ __launch_bounds__(256) void stream_outer_ileave(
        const float2* __restrict__ wsA, const float2* __restrict__ wsB,
        fvec4* __restrict__ out) {
    const int b = blockIdx.x, slice = blockIdx.y, t = threadIdx.x;
    const int jp = t & 127;
    const int half = t >> 7;
    const fvec4 bl = ((const fvec4*)(wsB + b * 256))[jp];  // cols 2jp,2jp+1
    const float2 b0 = make_float2(bl[0], bl[1]);
    const float2 b1 = make_float2(bl[2], bl[3]);
    fvec4* outb = out + (size_t)b * 32768;
    const int row0 = slice * 64 + half * 32;
    #pragma unroll 4
    for (int i = row0; i < row0 + 32; ++i) {
        const float2 ai = wsA[b * 256 + i];
        const float2 r0 = cmul(ai, b0), r1 = cmul(ai, b1);
        fvec4 w; w[0] = r0.x; w[1] = r0.y; w[2] = r1.x; w[3] = r1.y;
        __builtin_nontemporal_store(w, &outb[(size_t)i * 128 + jp]);
    }
}

extern "C" void kernel_launch(void* const* d_in, const int* in_sizes, int n_in,
                              void* d_out, int out_size, void* d_ws, size_t ws_size,
                              hipStream_t stream) {
    const float* ry = (const float*)d_in[0];
    const float* rz = (const float*)d_in[1];

    const int B = in_sizes[0] / 16;                 // 256
    const long long pairs = (long long)B << 16;     // 16,777,216 complexes
    float2* wsA = (float2*)d_ws;                    // [B*256]
    float2* wsB = wsA + (size_t)B * 256;            // [B*256]
    dim3 block(256, 1, 1);

    build_tables<<<dim3(B, 1, 1), block, 0, stream>>>(ry, rz, wsA, wsB);
    if ((long long)out_size >= 2 * pairs) {
        stream_outer_ileave<<<dim3(B, 4, 1), block, 0, stream>>>(wsA, wsB, (fvec4*)d_out);
    } else {
        stream_outer<<<dim3(B, 16, 1), block, 0, stream>>>(wsA, wsB, (fvec4*)d_out);
    }
}

// Round 11
// 78.627 us; speedup vs baseline: 1.0351x; 1.0351x over previous
//
#include <hip/hip_runtime.h>

// B=256, Q=16. v[idx] = prod_q cols[q][bit], qubit 0 = MSB.
// i = idx>>8 (qubits 0..7), j = idx&255 (qubits 8..15): v = A[i]*Bv[j].
// Output: fp32 real part, [B, 65536] (locked since R7; absmax 4.9e-4).
//
// R11: A/B test nt vs plain stores on the R9 structure.
//  - R10 falsified the prologue theory: a pure streamer (tables precomputed
//    in ws, no LDS/barriers/sincos) ran NO faster; split cost +3us launch.
//  - Harness fillBufferAligned sustains 6.1 TB/s with PLAIN dwordx4 stores;
//    our nt-store kernels sit at ~3.3 TB/s. Hypothesis: nt (L2-bypass,
//    64B-granule direct-to-HBM) is the slow path; plain stores ride the same
//    L2 writeback pipe as fillBuffer.
//  - Single kernel again (split regressed), grid (B,16), hoisted A reads,
//    4 plain float4 stores/thread.

__device__ __forceinline__ float2 cmul(float2 a, float2 b) {
    return make_float2(fmaf(a.x, b.x, -a.y * b.y),
                       fmaf(a.x, b.y,  a.y * b.x));
}

__device__ __forceinline__ void build_AB(const float* __restrict__ ry,
                                         const float* __restrict__ rz,
                                         int b, int t,
                                         float2 (&cols)[16][2],
                                         float2 (&A)[256], float2 (&Bv)[256]) {
    if (t < 16) {
        float hry = 0.5f * ry[b * 16 + t];
        float hrz = 0.5f * rz[b * 16 + t];
        float s, c, sz, cz;
        sincosf(hry, &s, &c);
        sincosf(hrz, &sz, &cz);
        cols[t][0] = make_float2(c * cz, -c * sz);  // cos(ry/2) e^{-i rz/2}
        cols[t][1] = make_float2(s * cz,  s * sz);  // sin(ry/2) e^{+i rz/2}
    }
    __syncthreads();
    float2 a = cols[0][(t >> 7) & 1];
    #pragma unroll
    for (int q = 1; q < 8; ++q) a = cmul(a, cols[q][(t >> (7 - q)) & 1]);
    A[t] = a;
    float2 bv = cols[8][(t >> 7) & 1];
    #pragma unroll
    for (int q = 9; q < 16; ++q) bv = cmul(bv, cols[q][(t >> (15 - q)) & 1]);
    Bv[t] = bv;
    __syncthreads();
}

// ---- primary: fp32 real part, [B, 65536], grid (B, 16), PLAIN stores ----
__global__ __launch_bounds__(256) void encoder_real_f32(
        const float* __restrict__ ry, const float* __restrict__ rz,
        float4* __restrict__ out) {
    __shared__ float2 cols[16][2];
    __shared__ float2 A[256];
    __shared__ float2 Bv[256];
    const int b = blockIdx.x, slice = blockIdx.y, t = threadIdx.x;
    build_AB(ry, rz, b, t, cols, A, Bv);

    const int jp = t & 63;     // float4 chunk within row
    const int wv = t >> 6;     // wave id 0..3
    const float2 b0 = Bv[4 * jp + 0], b1 = Bv[4 * jp + 1];
    const float2 b2 = Bv[4 * jp + 2], b3 = Bv[4 * jp + 3];

    const int row0 = slice * 16 + wv * 4;
    const float2 a0 = A[row0 + 0];   // wave-uniform broadcasts
    const float2 a1 = A[row0 + 1];
    const float2 a2 = A[row0 + 2];
    const float2 a3 = A[row0 + 3];

    float4* outb = out + (size_t)b * 16384 + (size_t)row0 * 64 + jp;
    float4 w0, w1, w2, w3;
    w0.x = fmaf(a0.x, b0.x, -a0.y * b0.y);
    w0.y = fmaf(a0.x, b1.x, -a0.y * b1.y);
    w0.z = fmaf(a0.x, b2.x, -a0.y * b2.y);
    w0.w = fmaf(a0.x, b3.x, -a0.y * b3.y);
    w1.x = fmaf(a1.x, b0.x, -a1.y * b0.y);
    w1.y = fmaf(a1.x, b1.x, -a1.y * b1.y);
    w1.z = fmaf(a1.x, b2.x, -a1.y * b2.y);
    w1.w = fmaf(a1.x, b3.x, -a1.y * b3.y);
    w2.x = fmaf(a2.x, b0.x, -a2.y * b0.y);
    w2.y = fmaf(a2.x, b1.x, -a2.y * b1.y);
    w2.z = fmaf(a2.x, b2.x, -a2.y * b2.y);
    w2.w = fmaf(a2.x, b3.x, -a2.y * b3.y);
    w3.x = fmaf(a3.x, b0.x, -a3.y * b0.y);
    w3.y = fmaf(a3.x, b1.x, -a3.y * b1.y);
    w3.z = fmaf(a3.x, b2.x, -a3.y * b2.y);
    w3.w = fmaf(a3.x, b3.x, -a3.y * b3.y);
    outb[  0] = w0;
    outb[ 64] = w1;
    outb[128] = w2;
    outb[192] = w3;
}

// ---- fallback (out_size == 2^25 fp32): interleaved re/im, grid (B, 4) ----
__global__ __launch_bounds__(256) void encoder_ileave_f32(
        const float* __restrict__ ry, const float* __restrict__ rz,
        float4* __restrict__ out) {
    __shared__ float2 cols[16][2];
    __shared__ float2 A[256];
    __shared__ float2 Bv[256];
    const int b = blockIdx.x, slice = blockIdx.y, t = threadIdx.x;
    build_AB(ry, rz, b, t, cols, A, Bv);

    const int jp   = t & 127;
    const int half = t >> 7;
    const float2 b0 = Bv[2 * jp], b1 = Bv[2 * jp + 1];
    float4* outb = out + (size_t)b * 32768;
    const int row0 = slice * 64 + half * 32;
    #pragma unroll 4
    for (int i = row0; i < row0 + 32; ++i) {
        const float2 ai = A[i];
        const float2 r0 = cmul(ai, b0), r1 = cmul(ai, b1);
        outb[(size_t)i * 128 + jp] = make_float4(r0.x, r0.y, r1.x, r1.y);
    }
}

extern "C" void kernel_launch(void* const* d_in, const int* in_sizes, int n_in,
                              void* d_out, int out_size, void* d_ws, size_t ws_size,
                              hipStream_t stream) {
    const float* ry = (const float*)d_in[0];
    const float* rz = (const float*)d_in[1];

    const int B = in_sizes[0] / 16;                 // 256
    const long long pairs = (long long)B << 16;     // 16,777,216 complexes
    dim3 block(256, 1, 1);
    if ((long long)out_size >= 2 * pairs) {
        dim3 grid(B, 4, 1);
        encoder_ileave_f32<<<grid, block, 0, stream>>>(ry, rz, (float4*)d_out);
    } else {
        dim3 grid(B, 16, 1);
        encoder_real_f32<<<grid, block, 0, stream>>>(ry, rz, (float4*)d_out);
    }
}